// Round 2
// baseline (296.950 us; speedup 1.0000x reference)
//
#include <hip/hip_runtime.h>

#pragma clang fp contract(off)

#define H_ 192
#define W_ 192
#define HW_ (192 * 192)
#define NSC 3
#define NCAND (NSC * HW_)
#define CCH 256
#define KMAX 2048

// d_out layout (floats), in reference return order:
// keypoints [2048,2], descriptors [2048,256], scores [2048], det0/1/2 [192,192]
#define KP_OFF 0
#define DESC_OFF (KMAX * 2)
#define SC_OFF (DESC_OFF + KMAX * CCH)
#define DET_OFF (SC_OFF + KMAX)

typedef unsigned long long u64;
typedef unsigned int u32;

// ws layout (bytes):
//       0 : fin keys  u64[NCAND]   (884736 B, worst-case capacity)
//  884736 : nfin      u32 (+pad to 64 B)
//  884800 : selbuf    u64[KMAX]    (16384 B)   (memset to 0 with nfin)

// Exact replica of the reference per-pixel math (NMS + handcrafted Newton
// localization). FP contraction is OFF for this TU so float ops match numpy
// bit-for-bit; tap order matches the conv's flattened tap order (zero taps
// are exact no-ops).
__device__ __forceinline__ void newton_pixel(const float* __restrict__ sm, int i, int j,
                                             float& det, float& ki, float& kj, bool& valid) {
    float v[3][3];
    float mx = -INFINITY;
#pragma unroll
    for (int a = 0; a < 3; ++a) {
#pragma unroll
        for (int b = 0; b < 3; ++b) {
            int ii = i + a - 1, jj = j + b - 1;
            bool in = (ii >= 0) && (ii < H_) && (jj >= 0) && (jj < W_);
            float val = in ? sm[ii * W_ + jj] : 0.0f;
            v[a][b] = val;
            if (in) mx = fmaxf(mx, val);
        }
    }
    float c = v[1][1];
    det = (mx == c) ? c : 0.0f;
    float di  = -0.5f * v[0][1] + 0.5f * v[2][1];
    float dj  = -0.5f * v[1][0] + 0.5f * v[1][2];
    float dii = v[0][1] - 2.0f * c + v[2][1];
    float djj = v[1][0] - 2.0f * c + v[1][2];
    float dij = 0.25f * v[0][0] - 0.25f * v[0][2] - 0.25f * v[2][0] + 0.25f * v[2][2];
    float dd = dii * djj - dij * dij;
    if (dd == 0.0f) dd = 1e-20f;
    float step_i = -(djj * di - dij * dj) / dd;
    float step_j = -(-dij * di + dii * dj) / dd;
    valid = (det != 0.0f) && (fabsf(step_i) < 0.5f) && (fabsf(step_j) < 0.5f);
    ki = valid ? ((float)i + step_i) : 0.0f;
    kj = valid ? ((float)j + step_j) : 0.0f;
    float i0 = floorf(ki), j0 = floorf(kj);
    valid = valid && (i0 >= 0.0f) && (j0 >= 0.0f) &&
            (i0 + 1.0f <= (float)(H_ - 1)) && (j0 + 1.0f <= (float)(W_ - 1));
}

// Kernel 1: per-pixel NMS/Newton; write det maps; append valid candidate keys
// (block-aggregated atomic append; order irrelevant, ranked later).
__global__ __launch_bounds__(256) void cand_kernel(
    const float* __restrict__ s0, const float* __restrict__ s1, const float* __restrict__ s2,
    float* __restrict__ out, u64* __restrict__ fin, u32* __restrict__ nfin) {
    __shared__ u32 lcnt, base;
    if (threadIdx.x == 0) lcnt = 0;
    __syncthreads();
    int t = blockIdx.x * 256 + threadIdx.x;
    bool valid = false;
    u64 key = 0;
    if (t < NCAND) {
        int s = t / HW_;
        int rem = t - s * HW_;
        int i = rem / W_;
        int j = rem - i * W_;
        const float* sm = (s == 0) ? s0 : (s == 1) ? s1 : s2;
        float det, ki, kj;
        newton_pixel(sm, i, j, det, ki, kj, valid);
        out[DET_OFF + t] = det;
        if (valid) {
            // det > 0 here; ordered-float of a positive value = bits | 0x80000000.
            u32 sb = __float_as_uint(det) | 0x80000000u;
            key = ((u64)sb << 32) | (u64)(0xFFFFFFFFu - (u32)t);  // ties -> lower idx first
        }
    }
    u32 lpos = 0;
    if (valid) lpos = atomicAdd(&lcnt, 1u);
    __syncthreads();
    if (threadIdx.x == 0 && lcnt > 0) base = atomicAdd(nfin, lcnt);
    __syncthreads();
    if (valid) fin[base + lpos] = key;
}

// Kernel 2: counting-rank selection, fully parallel. Keys are unique, so
// rank(key) = #{other keys > key} is an exact, collision-free output slot.
// Block = 256 threads = 64 keys x 4 sub-lanes; all-candidate tiles staged in
// LDS; rank < 2048 scatters the key to selbuf[rank]. selbuf pre-zeroed.
#define RK_KEYS 64
#define RK_TILE 2048
__global__ __launch_bounds__(256) void rank_kernel(
    const u64* __restrict__ fin, const u32* __restrict__ nfin, u64* __restrict__ selbuf) {
    __shared__ u64 tile[RK_TILE];
    u32 n = *nfin;
    u32 kbase = blockIdx.x * RK_KEYS;
    if (kbase >= n) return;  // uniform early-exit
    int tid = threadIdx.x;
    u32 kidx = kbase + ((u32)tid >> 2);
    u32 sub = (u32)tid & 3u;
    bool havekey = (kidx < n);
    u64 mykey = havekey ? fin[kidx] : 0ull;
    u32 cnt = 0;
    u32 ntiles = (n + RK_TILE - 1) / RK_TILE;
    for (u32 tb = 0; tb < ntiles; ++tb) {
        u32 base = tb * RK_TILE;
        for (u32 i = (u32)tid; i < RK_TILE; i += 256) {
            u32 gi = base + i;
            tile[i] = (gi < n) ? fin[gi] : 0ull;  // 0 sentinel never > a real key
        }
        __syncthreads();
        u32 lim = (n - base < RK_TILE) ? (n - base) : RK_TILE;
        for (u32 i = sub; i < lim; i += 4)
            cnt += (tile[i] > mykey) ? 1u : 0u;
        __syncthreads();
    }
    cnt += __shfl_down(cnt, 2, 4);
    cnt += __shfl_down(cnt, 1, 4);
    if (havekey && sub == 0 && cnt < KMAX) selbuf[cnt] = mykey;
}

// Kernel 3: one block (256 threads = 256 channels) per output slot.
// Recompute ki/kj for the winner pixel, bilinear-interp 256-ch descriptor,
// L2-normalize, emit keypoint/score. Invalid / padded slots -> zeros.
__global__ __launch_bounds__(256) void output_kernel(
    const u64* __restrict__ selbuf,
    const float* __restrict__ f0, const float* __restrict__ f1, const float* __restrict__ f2,
    const float* __restrict__ s0, const float* __restrict__ s1, const float* __restrict__ s2,
    float* __restrict__ out) {
    __shared__ float red[256];
    int r = blockIdx.x;
    int tid = threadIdx.x;
    u64 key = selbuf[r];
    u32 hi = (u32)(key >> 32);
    if (hi < 0x80000001u) {  // padding (0) — no finite det>0 key here
        out[DESC_OFF + r * CCH + tid] = 0.0f;
        if (tid == 0) {
            out[SC_OFF + r] = 0.0f;
            out[KP_OFF + r * 2 + 0] = 0.0f;
            out[KP_OFF + r * 2 + 1] = 0.0f;
        }
        return;
    }
    u32 gid = 0xFFFFFFFFu - (u32)(key & 0xFFFFFFFFull);
    int s = gid / HW_;
    int rem = gid - s * HW_;
    int i = rem / W_;
    int j = rem - i * W_;
    const float* sm = (s == 0) ? s0 : (s == 1) ? s1 : s2;
    const float* feat = (s == 0) ? f0 : (s == 1) ? f1 : f2;
    float det, ki, kj;
    bool valid;
    newton_pixel(sm, i, j, det, ki, kj, valid);  // valid guaranteed true here
    int i0 = (int)floorf(ki), j0 = (int)floorf(kj);
    float wi = ki - (float)i0;
    float wj = kj - (float)j0;
    const float* p = feat + (size_t)tid * HW_ + i0 * W_ + j0;
    float f00 = p[0], f01 = p[1], f10 = p[W_], f11 = p[W_ + 1];
    float d = f00 * (1.0f - wi) * (1.0f - wj) + f01 * (1.0f - wi) * wj +
              f10 * wi * (1.0f - wj) + f11 * wi * wj;
    red[tid] = d * d;
    __syncthreads();
    for (int st = 128; st > 0; st >>= 1) {
        if (tid < st) red[tid] += red[tid + st];
        __syncthreads();
    }
    float norm = fmaxf(sqrtf(red[0]), 1e-12f);
    out[DESC_OFF + r * CCH + tid] = d / norm;
    if (tid == 0) {
        out[SC_OFF + r] = __uint_as_float(hi & 0x7FFFFFFFu);  // invert ordered-float (positive)
        float x = kj, y = ki;
#pragma unroll
        for (int u = 0; u < 4; ++u) { x = x * 2.0f + 0.5f; y = y * 2.0f + 0.5f; }
        out[KP_OFF + r * 2 + 0] = x;  // (x=col, y=row) per reference [:, [1,0]] swap
        out[KP_OFF + r * 2 + 1] = y;
    }
}

extern "C" void kernel_launch(void* const* d_in, const int* in_sizes, int n_in,
                              void* d_out, int out_size, void* d_ws, size_t ws_size,
                              hipStream_t stream) {
    const float* f0 = (const float*)d_in[0];
    const float* f1 = (const float*)d_in[1];
    const float* f2 = (const float*)d_in[2];
    const float* s0 = (const float*)d_in[3];
    const float* s1 = (const float*)d_in[4];
    const float* s2 = (const float*)d_in[5];
    float* out = (float*)d_out;

    char* ws = (char*)d_ws;
    u64* fin = (u64*)ws;                     // 884736 B
    u32* nfin = (u32*)(ws + 884736);         // 64 B (counter + pad)
    u64* selbuf = (u64*)(ws + 884800);       // 16384 B

    // zero counter + selbuf (padding rows rely on 0-keys) in one memset
    hipMemsetAsync(ws + 884736, 0, 64 + KMAX * sizeof(u64), stream);
    cand_kernel<<<NCAND / 256, 256, 0, stream>>>(s0, s1, s2, out, fin, nfin);
    rank_kernel<<<(NCAND + RK_KEYS - 1) / RK_KEYS, 256, 0, stream>>>(fin, nfin, selbuf);
    output_kernel<<<KMAX, 256, 0, stream>>>(selbuf, f0, f1, f2, s0, s1, s2, out);
}

// Round 3
// 168.851 us; speedup vs baseline: 1.7587x; 1.7587x over previous
//
#include <hip/hip_runtime.h>

#pragma clang fp contract(off)

#define H_ 192
#define W_ 192
#define HW_ (192 * 192)
#define NSC 3
#define NCAND (NSC * HW_)
#define CCH 256
#define KMAX 2048
#define NBIN 4096
#define SURV_CAP 8192
#define RTILE 4096

// d_out layout (floats), in reference return order:
// keypoints [2048,2], descriptors [2048,256], scores [2048], det0/1/2 [192,192]
#define KP_OFF 0
#define DESC_OFF (KMAX * 2)
#define SC_OFF (DESC_OFF + KMAX * CCH)
#define DET_OFF (SC_OFF + KMAX)

typedef unsigned long long u64;
typedef unsigned int u32;

// ws layout (bytes):
//      0 : fin keys   u64[NCAND]     884736
// 884736 : counters   u32[16]        64      [0]=nfin [1]=thr_bin [2]=nsurv
// 884800 : selbuf     u64[KMAX]      16384   (memset 0: padding rows)
// 901184 : ghist      u32[NBIN]      16384   (memset 0)
// 917568 : surv       u64[SURV_CAP]  65536
#define CNT_OFF 884736
#define SEL_OFF 884800
#define GH_OFF 901184
#define SURV_OFF 917568

// Order-monotone bin of a key's high word (positive ordered-float bits).
__device__ __forceinline__ u32 key_bin(u32 sb) { return (sb >> 19) & (NBIN - 1); }

// Exact replica of the reference per-pixel math (NMS + handcrafted Newton
// localization). FP contraction is OFF for this TU so float ops match numpy
// bit-for-bit.
__device__ __forceinline__ void newton_pixel(const float* __restrict__ sm, int i, int j,
                                             float& det, float& ki, float& kj, bool& valid) {
    float v[3][3];
    float mx = -INFINITY;
#pragma unroll
    for (int a = 0; a < 3; ++a) {
#pragma unroll
        for (int b = 0; b < 3; ++b) {
            int ii = i + a - 1, jj = j + b - 1;
            bool in = (ii >= 0) && (ii < H_) && (jj >= 0) && (jj < W_);
            float val = in ? sm[ii * W_ + jj] : 0.0f;
            v[a][b] = val;
            if (in) mx = fmaxf(mx, val);
        }
    }
    float c = v[1][1];
    det = (mx == c) ? c : 0.0f;
    float di  = -0.5f * v[0][1] + 0.5f * v[2][1];
    float dj  = -0.5f * v[1][0] + 0.5f * v[1][2];
    float dii = v[0][1] - 2.0f * c + v[2][1];
    float djj = v[1][0] - 2.0f * c + v[1][2];
    float dij = 0.25f * v[0][0] - 0.25f * v[0][2] - 0.25f * v[2][0] + 0.25f * v[2][2];
    float dd = dii * djj - dij * dij;
    if (dd == 0.0f) dd = 1e-20f;
    float step_i = -(djj * di - dij * dj) / dd;
    float step_j = -(-dij * di + dii * dj) / dd;
    valid = (det != 0.0f) && (fabsf(step_i) < 0.5f) && (fabsf(step_j) < 0.5f);
    ki = valid ? ((float)i + step_i) : 0.0f;
    kj = valid ? ((float)j + step_j) : 0.0f;
    float i0 = floorf(ki), j0 = floorf(kj);
    valid = valid && (i0 >= 0.0f) && (j0 >= 0.0f) &&
            (i0 + 1.0f <= (float)(H_ - 1)) && (j0 + 1.0f <= (float)(W_ - 1));
}

// Kernel 1: per-pixel NMS/Newton; det maps; append valid keys; fused LDS->
// global score-bin histogram for the selection prune.
__global__ __launch_bounds__(256) void cand_kernel(
    const float* __restrict__ s0, const float* __restrict__ s1, const float* __restrict__ s2,
    float* __restrict__ out, u64* __restrict__ fin, u32* __restrict__ cnts,
    u32* __restrict__ ghist) {
    __shared__ u32 lh[NBIN];
    __shared__ u32 lcnt, base;
    int tid = threadIdx.x;
    for (int i = tid; i < NBIN; i += 256) lh[i] = 0;
    if (tid == 0) lcnt = 0;
    __syncthreads();
    int t = blockIdx.x * 256 + tid;
    bool valid = false;
    u64 key = 0;
    {
        int s = t / HW_;
        int rem = t - s * HW_;
        int i = rem / W_;
        int j = rem - i * W_;
        const float* sm = (s == 0) ? s0 : (s == 1) ? s1 : s2;
        float det, ki, kj;
        newton_pixel(sm, i, j, det, ki, kj, valid);
        out[DET_OFF + t] = det;
        if (valid) {
            u32 sb = __float_as_uint(det) | 0x80000000u;  // det>0: ordered bits
            key = ((u64)sb << 32) | (u64)(0xFFFFFFFFu - (u32)t);  // ties: lower idx first
            atomicAdd(&lh[key_bin(sb)], 1u);
        }
    }
    u32 lpos = 0;
    if (valid) lpos = atomicAdd(&lcnt, 1u);
    __syncthreads();
    if (tid == 0 && lcnt > 0) base = atomicAdd(&cnts[0], lcnt);
    __syncthreads();
    if (valid) fin[base + lpos] = key;
    for (int i = tid; i < NBIN; i += 256)
        if (lh[i]) atomicAdd(&ghist[i], lh[i]);
}

// Kernel 2 (1 block, 1024 thr): suffix-scan the 4096-bin histogram, pick the
// threshold bin b* = max{b : #keys with bin>=b >= 2048} (or 0 if n<=2048).
__global__ __launch_bounds__(1024) void scan_kernel(
    const u32* __restrict__ ghist, u32* __restrict__ cnts) {
    __shared__ u32 s[NBIN];
    int tid = threadIdx.x;
#pragma unroll
    for (int r = 0; r < 4; ++r) s[tid + r * 1024] = ghist[tid + r * 1024];
    __syncthreads();
    for (u32 off = 1; off < NBIN; off <<= 1) {
        u32 v[4];
#pragma unroll
        for (int r = 0; r < 4; ++r) {
            u32 i = tid + r * 1024;
            v[r] = s[i] + ((i + off < NBIN) ? s[i + off] : 0u);
        }
        __syncthreads();
#pragma unroll
        for (int r = 0; r < 4; ++r) s[tid + r * 1024] = v[r];
        __syncthreads();
    }
    u32 n = cnts[0];
    if (n <= KMAX) {
        if (tid == 0) cnts[1] = 0;
    } else {
#pragma unroll
        for (int r = 0; r < 4; ++r) {
            u32 b = tid + r * 1024;
            if (s[b] >= KMAX && (b == NBIN - 1 || s[b + 1] < KMAX)) cnts[1] = b;
        }
    }
}

// Kernel 3: compact survivors (bin >= b*) — grid-strided, order irrelevant.
__global__ __launch_bounds__(256) void compact_kernel(
    const u64* __restrict__ fin, u32* __restrict__ cnts, u64* __restrict__ surv) {
    u32 n = cnts[0], thr = cnts[1];
    for (u32 i = blockIdx.x * 256 + threadIdx.x; i < n; i += 256 * 256) {
        u64 key = fin[i];
        if (key_bin((u32)(key >> 32)) >= thr) {
            u32 pos = atomicAdd(&cnts[2], 1u);
            if (pos < SURV_CAP) surv[pos] = key;
        }
    }
}

// Kernel 4: exact rank among survivors (== global rank, since all pruned keys
// are strictly smaller). One WAVE per key; survivors staged in a shared LDS
// tile; lanes stride the tile; 6-step shuffle reduce; scatter to selbuf[rank].
__global__ __launch_bounds__(256) void rank_kernel(
    const u64* __restrict__ surv, const u32* __restrict__ cnts, u64* __restrict__ selbuf) {
    __shared__ u64 tile[RTILE];
    u32 m = cnts[2];
    if (m > SURV_CAP) m = SURV_CAP;
    int tid = threadIdx.x;
    u32 lane = (u32)tid & 63u;
    u32 waveg = blockIdx.x * 4 + ((u32)tid >> 6);  // global wave id = key slot
    for (u32 kbase = 0; kbase < SURV_CAP; kbase += RTILE) {
        if (kbase >= m) break;  // uniform
        u32 k = kbase + waveg;
        bool have = (k < m);
        u64 mykey = have ? surv[k] : 0ull;
        u32 cnt = 0;
        for (u32 tb = 0; tb < m; tb += RTILE) {
            for (u32 i = (u32)tid; i < RTILE; i += 256) {
                u32 gi = tb + i;
                tile[i] = (gi < m) ? surv[gi] : 0ull;
            }
            __syncthreads();
            u32 lim = (m - tb < RTILE) ? (m - tb) : RTILE;
            for (u32 i = lane; i < lim; i += 64)
                cnt += (tile[i] > mykey) ? 1u : 0u;
            __syncthreads();
        }
#pragma unroll
        for (int o = 32; o > 0; o >>= 1) cnt += __shfl_down(cnt, o, 64);
        if (have && lane == 0 && cnt < KMAX) selbuf[cnt] = mykey;
    }
}

// Kernel 5: one block (256 threads = 256 channels) per output slot.
__global__ __launch_bounds__(256) void output_kernel(
    const u64* __restrict__ selbuf,
    const float* __restrict__ f0, const float* __restrict__ f1, const float* __restrict__ f2,
    const float* __restrict__ s0, const float* __restrict__ s1, const float* __restrict__ s2,
    float* __restrict__ out) {
    __shared__ float red[256];
    int r = blockIdx.x;
    int tid = threadIdx.x;
    u64 key = selbuf[r];
    u32 hi = (u32)(key >> 32);
    if (hi < 0x80000001u) {  // padding (0-key): zero row
        out[DESC_OFF + r * CCH + tid] = 0.0f;
        if (tid == 0) {
            out[SC_OFF + r] = 0.0f;
            out[KP_OFF + r * 2 + 0] = 0.0f;
            out[KP_OFF + r * 2 + 1] = 0.0f;
        }
        return;
    }
    u32 gid = 0xFFFFFFFFu - (u32)(key & 0xFFFFFFFFull);
    int s = gid / HW_;
    int rem = gid - s * HW_;
    int i = rem / W_;
    int j = rem - i * W_;
    const float* sm = (s == 0) ? s0 : (s == 1) ? s1 : s2;
    const float* feat = (s == 0) ? f0 : (s == 1) ? f1 : f2;
    float det, ki, kj;
    bool valid;
    newton_pixel(sm, i, j, det, ki, kj, valid);  // valid guaranteed here
    int i0 = (int)floorf(ki), j0 = (int)floorf(kj);
    float wi = ki - (float)i0;
    float wj = kj - (float)j0;
    const float* p = feat + (size_t)tid * HW_ + i0 * W_ + j0;
    float f00 = p[0], f01 = p[1], f10 = p[W_], f11 = p[W_ + 1];
    float d = f00 * (1.0f - wi) * (1.0f - wj) + f01 * (1.0f - wi) * wj +
              f10 * wi * (1.0f - wj) + f11 * wi * wj;
    red[tid] = d * d;
    __syncthreads();
    for (int st = 128; st > 0; st >>= 1) {
        if (tid < st) red[tid] += red[tid + st];
        __syncthreads();
    }
    float norm = fmaxf(sqrtf(red[0]), 1e-12f);
    out[DESC_OFF + r * CCH + tid] = d / norm;
    if (tid == 0) {
        out[SC_OFF + r] = __uint_as_float(hi & 0x7FFFFFFFu);
        float x = kj, y = ki;
#pragma unroll
        for (int u = 0; u < 4; ++u) { x = x * 2.0f + 0.5f; y = y * 2.0f + 0.5f; }
        out[KP_OFF + r * 2 + 0] = x;  // (x=col, y=row)
        out[KP_OFF + r * 2 + 1] = y;
    }
}

extern "C" void kernel_launch(void* const* d_in, const int* in_sizes, int n_in,
                              void* d_out, int out_size, void* d_ws, size_t ws_size,
                              hipStream_t stream) {
    const float* f0 = (const float*)d_in[0];
    const float* f1 = (const float*)d_in[1];
    const float* f2 = (const float*)d_in[2];
    const float* s0 = (const float*)d_in[3];
    const float* s1 = (const float*)d_in[4];
    const float* s2 = (const float*)d_in[5];
    float* out = (float*)d_out;

    char* ws = (char*)d_ws;
    u64* fin = (u64*)ws;
    u32* cnts = (u32*)(ws + CNT_OFF);
    u64* selbuf = (u64*)(ws + SEL_OFF);
    u32* ghist = (u32*)(ws + GH_OFF);
    u64* surv = (u64*)(ws + SURV_OFF);

    // zero counters + selbuf + ghist in one memset
    hipMemsetAsync(ws + CNT_OFF, 0, 64 + KMAX * 8 + NBIN * 4, stream);
    cand_kernel<<<NCAND / 256, 256, 0, stream>>>(s0, s1, s2, out, fin, cnts, ghist);
    scan_kernel<<<1, 1024, 0, stream>>>(ghist, cnts);
    compact_kernel<<<256, 256, 0, stream>>>(fin, cnts, surv);
    rank_kernel<<<SURV_CAP / 4, 256, 0, stream>>>(surv, cnts, selbuf);
    output_kernel<<<KMAX, 256, 0, stream>>>(selbuf, f0, f1, f2, s0, s1, s2, out);
}